// Round 6
// baseline (241.084 us; speedup 1.0000x reference)
//
#include <hip/hip_runtime.h>

#define NH 8
#define HD 32
#define SUMP 16
#define LQ 4096
#define BS 4
#define LV 8500
#define NQ (BS * LQ)   // 16384
#define MV (BS * LV)   // 34000

typedef short s16x8 __attribute__((ext_vector_type(8)));
typedef float f32x4 __attribute__((ext_vector_type(4)));
typedef _Float16 h16x4 __attribute__((ext_vector_type(4)));

__device__ __forceinline__ float bf2f(unsigned short u) {
    union { unsigned int i; float f; } x; x.i = ((unsigned int)u) << 16; return x.f;
}
__device__ __forceinline__ unsigned short f2bf(float f) {
    union { float f; unsigned int i; } x; x.f = f;
    unsigned int r = x.i + 0x7fffu + ((x.i >> 16) & 1u);
    return (unsigned short)(r >> 16);
}
__device__ __forceinline__ void split8(const float* f, s16x8& hi, s16x8& lo) {
    #pragma unroll
    for (int i = 0; i < 8; ++i) {
        unsigned short h = f2bf(f[i]);
        float r = f[i] - bf2f(h);
        hi[i] = (short)h;
        lo[i] = (short)f2bf(r);
    }
}

// ---------- prep: transpose + split weights into Wt_hi/Wt_lo [N][K], concat biases ----------
__global__ __launch_bounds__(256) void prep_kernel(
    const float* __restrict__ Wv, const float* __restrict__ Woff,
    const float* __restrict__ Wattn, const float* __restrict__ Wo,
    const float* __restrict__ boff, const float* __restrict__ battn,
    unsigned short* __restrict__ WtVh, unsigned short* __restrict__ WtVl,
    unsigned short* __restrict__ WtOAh, unsigned short* __restrict__ WtOAl,
    unsigned short* __restrict__ WtOh, unsigned short* __restrict__ WtOl,
    float* __restrict__ biasOA)
{
    int r = blockIdx.x;      // 0..895
    int k = threadIdx.x;     // 0..255
    float w; unsigned short* ph; unsigned short* pl; size_t idx;
    if (r < 256)      { w = Wv[k * 256 + r];                 ph = WtVh;  pl = WtVl;  idx = (size_t)r * 256 + k; }
    else if (r < 512) { int n = r - 256; w = Woff[k * 256 + n];  ph = WtOAh; pl = WtOAl; idx = (size_t)n * 256 + k; }
    else if (r < 640) { int n = r - 512; w = Wattn[k * 128 + n]; ph = WtOAh; pl = WtOAl; idx = (size_t)(256 + n) * 256 + k; }
    else              { int n = r - 640; w = Wo[k * 256 + n];    ph = WtOh;  pl = WtOl;  idx = (size_t)n * 256 + k; }
    unsigned short h = f2bf(w);
    float res = w - bf2f(h);
    ph[idx] = h;
    pl[idx] = f2bf(res);
    if (r == 0) biasOA[k] = boff[k];
    if (r == 1 && k < 128) biasOA[256 + k] = battn[k];
}

// ---------- LDS-free fragment GEMM: C[M][N] = A[M][256] @ Bt[N][256]^T + bias ----------
// Block = 4 waves, 2x2 tiling, wave tile 64x64. No LDS, no barriers.
// A fp32, split to bf16 hi/lo in-register. B pre-split bf16 planes (L2-resident).

template <bool V_MODE>
__device__ __forceinline__ void gemm_frag_body(
    const float* __restrict__ A,
    const unsigned short* __restrict__ Bth, const unsigned short* __restrict__ Btl,
    const float* __restrict__ bias, void* __restrict__ Cv,
    int M, int mb, int nb)
{
    const int t = threadIdx.x;
    const int wave = t >> 6, lane = t & 63;
    const int quad = lane >> 4, l16 = lane & 15;
    const int mbase = mb * 128 + (wave & 1) * 64;
    const int nbase = nb * 128 + (wave >> 1) * 64;

    const float* aptr[4];
    const unsigned short* bhp[4];
    const unsigned short* blp[4];
    #pragma unroll
    for (int mi = 0; mi < 4; ++mi) {
        int r = mbase + mi * 16 + l16; if (r > M - 1) r = M - 1;  // clamp: rows>=M unused
        aptr[mi] = A + (size_t)r * 256 + quad * 8;
    }
    #pragma unroll
    for (int ni = 0; ni < 4; ++ni) {
        int n = nbase + ni * 16 + l16;
        bhp[ni] = Bth + (size_t)n * 256 + quad * 8;
        blp[ni] = Btl + (size_t)n * 256 + quad * 8;
    }

    float a_f[4][8];                  // single fp32 A buffer (loads for k+1 overlap MFMA k)
    s16x8 b_h[2][4], b_l[2][4];       // B double buffer
    f32x4 acc[4][4] = {};

    #pragma unroll
    for (int mi = 0; mi < 4; ++mi) {
        *(float4*)(a_f[mi] + 0) = *(const float4*)(aptr[mi] + 0);
        *(float4*)(a_f[mi] + 4) = *(const float4*)(aptr[mi] + 4);
    }
    #pragma unroll
    for (int ni = 0; ni < 4; ++ni) {
        b_h[0][ni] = *(const s16x8*)(bhp[ni]);
        b_l[0][ni] = *(const s16x8*)(blp[ni]);
    }

    #pragma unroll
    for (int k = 0; k < 8; ++k) {
        const int cur = k & 1, nxt = cur ^ 1;
        // consume current A fp32 -> bf16 hi/lo
        s16x8 ah[4], al[4];
        #pragma unroll
        for (int mi = 0; mi < 4; ++mi) split8(a_f[mi], ah[mi], al[mi]);
        if (k < 7) {
            const int k0 = (k + 1) * 32;
            #pragma unroll
            for (int mi = 0; mi < 4; ++mi) {
                *(float4*)(a_f[mi] + 0) = *(const float4*)(aptr[mi] + k0);
                *(float4*)(a_f[mi] + 4) = *(const float4*)(aptr[mi] + k0 + 4);
            }
            #pragma unroll
            for (int ni = 0; ni < 4; ++ni) {
                b_h[nxt][ni] = *(const s16x8*)(bhp[ni] + k0);
                b_l[nxt][ni] = *(const s16x8*)(blp[ni] + k0);
            }
        }
        #pragma unroll
        for (int mi = 0; mi < 4; ++mi) {
            #pragma unroll
            for (int ni = 0; ni < 4; ++ni) {
                acc[mi][ni] = __builtin_amdgcn_mfma_f32_16x16x32_bf16(ah[mi], b_h[cur][ni], acc[mi][ni], 0, 0, 0);
                acc[mi][ni] = __builtin_amdgcn_mfma_f32_16x16x32_bf16(ah[mi], b_l[cur][ni], acc[mi][ni], 0, 0, 0);
                acc[mi][ni] = __builtin_amdgcn_mfma_f32_16x16x32_bf16(al[mi], b_h[cur][ni], acc[mi][ni], 0, 0, 0);
            }
        }
    }

    // epilogue: C/D layout col=lane&15, row=quad*4+reg
    if (V_MODE) {
        // out: fp16 head-major [b][h][pos][32]
        #pragma unroll
        for (int mi = 0; mi < 4; ++mi) {
            int mq = mbase + mi * 16 + quad * 4;
            size_t rb[4]; int vld[4];
            #pragma unroll
            for (int r = 0; r < 4; ++r) {
                int m = mq + r;
                vld[r] = (m < M);
                int b = m / LV;
                int pos = m - b * LV;
                rb[r] = ((size_t)b * (NH * LV) + pos) * 32;
            }
            #pragma unroll
            for (int ni = 0; ni < 4; ++ni) {
                int n = nbase + ni * 16 + l16;
                float bv = bias[n];
                int h = n >> 5, d = n & 31;
                size_t ho = (size_t)h * (LV * 32) + d;
                #pragma unroll
                for (int r = 0; r < 4; ++r)
                    if (vld[r]) ((_Float16*)Cv)[rb[r] + ho] = (_Float16)(acc[mi][ni][r] + bv);
            }
        }
    } else {
        // out: fp32 row-major [NQ][384]
        #pragma unroll
        for (int ni = 0; ni < 4; ++ni) {
            int n = nbase + ni * 16 + l16;
            float bv = bias[n];
            #pragma unroll
            for (int mi = 0; mi < 4; ++mi) {
                int mq = mbase + mi * 16 + quad * 4;
                #pragma unroll
                for (int r = 0; r < 4; ++r)
                    ((float*)Cv)[(size_t)(mq + r) * 384 + n] = acc[mi][ni][r] + bv;
            }
        }
    }
}

__global__ __launch_bounds__(256, 2) void gemm_dual_kernel(
    const float* __restrict__ value, const unsigned short* __restrict__ WtVh,
    const unsigned short* __restrict__ WtVl, const float* __restrict__ b_v,
    _Float16* __restrict__ v_f16,
    const float* __restrict__ query, const unsigned short* __restrict__ WtOAh,
    const unsigned short* __restrict__ WtOAl, const float* __restrict__ biasOA,
    float* __restrict__ oa)
{
    int bid = blockIdx.x;
    if (bid < 532) {          // V: 266 m-blocks x 2 n-blocks
        gemm_frag_body<true>(value, WtVh, WtVl, b_v, v_f16, MV, bid % 266, bid / 266);
    } else {                  // OA: 128 m-blocks x 3 n-blocks
        int q = bid - 532;
        gemm_frag_body<false>(query, WtOAh, WtOAl, biasOA, oa, NQ, q % 128, q / 128);
    }
}

// ---------- fused sampling + output GEMM: 16 queries per block ----------
__global__ __launch_bounds__(256) void sample_out_kernel(
    const _Float16* __restrict__ v,          // [b][h][LV][32] fp16
    const float* __restrict__ oa,            // [NQ][384]: 0..255 offsets, 256..383 logits
    const float* __restrict__ refp,          // [NQ][4]
    const unsigned short* __restrict__ WtOh, const unsigned short* __restrict__ WtOl,
    const float* __restrict__ b_o,
    float* __restrict__ out)                 // [NQ][256] fp32
{
    const int row0 = blockIdx.x * 16;
    const int t = threadIdx.x;
    const int wave = t >> 6, lane = t & 63;
    const int quad = lane >> 4, l16 = lane & 15;

    __shared__ __align__(16) char smem[70144];
    float*  s_lx  = (float*)smem;                     // [16][128]  (union A)
    float*  s_ly  = (float*)(smem + 8192);
    float*  s_raw = (float*)(smem + 16384);
    int*    s_idx = (int*)smem;                       // [16*8][17] (union B)
    int*    s_dxy = (int*)(smem + 8704);
    float4* s_w4  = (float4*)(smem + 17408);
    float*  s_mx  = (float*)(smem + 52224);           // [16*8]
    float*  s_is  = (float*)(smem + 52736);
    unsigned short* s_mid = (unsigned short*)(smem + 53248);  // [2][16][264] bf16

    // --- P1: locations + raw logits (2048 entries) ---
    #pragma unroll
    for (int it = 0; it < 8; ++it) {
        int i = t + it * 256;
        int q = i >> 7, e = i & 127;          // e = h*16 + p
        int row = row0 + q;
        float4 r4 = *(const float4*)(refp + (size_t)row * 4);
        float2 o2 = *(const float2*)(oa + (size_t)row * 384 + e * 2);
        s_lx[q * 128 + e]  = r4.x + o2.x * 0.125f * r4.z;
        s_ly[q * 128 + e]  = r4.y + o2.y * 0.125f * r4.w;
        s_raw[q * 128 + e] = oa[(size_t)row * 384 + 256 + e];
    }
    __syncthreads();
    // --- P2: softmax stats, one (q,h) per thread ---
    if (t < 128) {
        int q = t >> 3, h = t & 7;
        float mx = -1e30f;
        #pragma unroll
        for (int p = 0; p < SUMP; ++p) mx = fmaxf(mx, s_raw[q * 128 + h * 16 + p]);
        float sm = 0.f;
        #pragma unroll
        for (int p = 0; p < SUMP; ++p) sm += __expf(s_raw[q * 128 + h * 16 + p] - mx);
        s_mx[t] = mx; s_is[t] = 1.f / sm;
    }
    __syncthreads();
    // --- P3: corner weights + offsets into regs, then overlay store ---
    int r_idx[8], r_dxy[8];
    float4 r_w4[8];
    #pragma unroll
    for (int it = 0; it < 8; ++it) {
        int i = t + it * 256;
        int q = i >> 7, e = i & 127, h = e >> 4, p = e & 15, l = p >> 2;
        int Wl = 80 >> l;
        int vst = (l == 0) ? 0 : (l == 1) ? 6400 : (l == 2) ? 8000 : 8400;
        float w = __expf(s_raw[q * 128 + e] - s_mx[q * 8 + h]) * s_is[q * 8 + h];
        float x = s_lx[q * 128 + e] * Wl - 0.5f;
        float y = s_ly[q * 128 + e] * Wl - 0.5f;
        float x0f = floorf(x), y0f = floorf(y);
        float lx = x - x0f, ly = y - y0f;
        int x0 = (int)x0f, y0 = (int)y0f;
        int x1 = x0 + 1, y1 = y0 + 1;
        float mx0 = (x0 >= 0 && x0 < Wl) ? 1.f : 0.f;
        float mx1 = (x1 >= 0 && x1 < Wl) ? 1.f : 0.f;
        float my0 = (y0 >= 0 && y0 < Wl) ? 1.f : 0.f;
        float my1 = (y1 >= 0 && y1 < Wl) ? 1.f : 0.f;
        int cx0 = min(max(x0, 0), Wl - 1), cx1 = min(max(x1, 0), Wl - 1);
        int cy0 = min(max(y0, 0), Wl - 1), cy1 = min(max(y1, 0), Wl - 1);
        r_idx[it] = (vst + cy0 * Wl + cx0) * 64;
        r_dxy[it] = ((cx1 - cx0) * 64) | (((cy1 - cy0) * Wl * 64) << 16);
        float4 w4;
        w4.x = w * (1.f - lx) * (1.f - ly) * mx0 * my0;
        w4.y = w * lx * (1.f - ly) * mx1 * my0;
        w4.z = w * (1.f - lx) * ly * mx0 * my1;
        w4.w = w * lx * ly * mx1 * my1;
        r_w4[it] = w4;
    }
    __syncthreads();   // all reads of union-A done before overlay write
    #pragma unroll
    for (int it = 0; it < 8; ++it) {
        int i = t + it * 256;
        int q = i >> 7, e = i & 127, h = e >> 4, p = e & 15;
        int s = (q * 8 + h) * 17 + p;
        s_idx[s] = r_idx[it]; s_dxy[s] = r_dxy[it]; s_w4[s] = r_w4[it];
    }
    __syncthreads();
    // --- P4: gather (wave = query within group of 4; 4 groups sequential) ---
    {
        const int h = (lane >> 3) & 7, dv = lane & 7;
        #pragma unroll
        for (int qi = 0; qi < 4; ++qi) {
            int q = qi * 4 + wave;
            int row = row0 + q;
            int b = row >> 12;                // LQ = 4096
            const char* vb = (const char*)v + ((size_t)(b * NH + h) * LV) * 64 + dv * 8;
            f32x4 a = {};
            #pragma unroll
            for (int p = 0; p < 16; ++p) {
                int s = (q * 8 + h) * 17 + p;
                int base = s_idx[s];
                int dxy = s_dxy[s];
                int dx = dxy & 0xffff, dy = dxy >> 16;
                float4 w4 = s_w4[s];
                h16x4 g00 = *(const h16x4*)(vb + base);
                h16x4 g01 = *(const h16x4*)(vb + base + dx);
                h16x4 g10 = *(const h16x4*)(vb + base + dy);
                h16x4 g11 = *(const h16x4*)(vb + base + dx + dy);
                #pragma unroll
                for (int c = 0; c < 4; ++c)
                    a[c] += w4.x * (float)g00[c] + w4.y * (float)g01[c]
                          + w4.z * (float)g10[c] + w4.w * (float)g11[c];
            }
            int mo = q * 264 + h * 32 + dv * 4;
            #pragma unroll
            for (int c = 0; c < 4; ++c) {
                unsigned short hv = f2bf(a[c]);
                s_mid[mo + c] = hv;
                s_mid[4224 + mo + c] = f2bf(a[c] - bf2f(hv));
            }
        }
    }
    __syncthreads();
    // --- P5: out = mid @ W_o + b_o (barrier-free MFMA; A from LDS, B from global) ---
    {
        const int nbase = wave * 64;
        const unsigned short* bhp[4];
        const unsigned short* blp[4];
        #pragma unroll
        for (int ni = 0; ni < 4; ++ni) {
            int n = nbase + ni * 16 + l16;
            bhp[ni] = WtOh + (size_t)n * 256 + quad * 8;
            blp[ni] = WtOl + (size_t)n * 256 + quad * 8;
        }
        f32x4 acc[4] = {};
        #pragma unroll
        for (int k0 = 0; k0 < 256; k0 += 32) {
            s16x8 ah = *(const s16x8*)(s_mid + l16 * 264 + k0 + quad * 8);
            s16x8 al = *(const s16x8*)(s_mid + 4224 + l16 * 264 + k0 + quad * 8);
            #pragma unroll
            for (int ni = 0; ni < 4; ++ni) {
                s16x8 bh = *(const s16x8*)(bhp[ni] + k0);
                s16x8 bl = *(const s16x8*)(blp[ni] + k0);
                acc[ni] = __builtin_amdgcn_mfma_f32_16x16x32_bf16(ah, bh, acc[ni], 0, 0, 0);
                acc[ni] = __builtin_amdgcn_mfma_f32_16x16x32_bf16(ah, bl, acc[ni], 0, 0, 0);
                acc[ni] = __builtin_amdgcn_mfma_f32_16x16x32_bf16(al, bh, acc[ni], 0, 0, 0);
            }
        }
        #pragma unroll
        for (int ni = 0; ni < 4; ++ni) {
            int n = nbase + ni * 16 + l16;
            float bv = b_o[n];
            #pragma unroll
            for (int r = 0; r < 4; ++r) {
                int m = quad * 4 + r;
                out[(size_t)(row0 + m) * 256 + n] = acc[ni][r] + bv;
            }
        }
    }
}

extern "C" void kernel_launch(void* const* d_in, const int* in_sizes, int n_in,
                              void* d_out, int out_size, void* d_ws, size_t ws_size,
                              hipStream_t stream) {
    const float* query  = (const float*)d_in[0];   // [4,4096,256]
    const float* refp   = (const float*)d_in[1];   // [4,4096,1,4]
    const float* value  = (const float*)d_in[2];   // [4,8500,256]
    const float* W_off  = (const float*)d_in[3];   // [256,256]
    const float* b_off  = (const float*)d_in[4];   // [256]
    const float* W_attn = (const float*)d_in[5];   // [256,128]
    const float* b_attn = (const float*)d_in[6];   // [128]
    const float* W_v    = (const float*)d_in[7];   // [256,256]
    const float* b_v    = (const float*)d_in[8];   // [256]
    const float* W_o    = (const float*)d_in[9];   // [256,256]
    const float* b_o    = (const float*)d_in[10];  // [256]

    char* ws = (char*)d_ws;
    _Float16*       v_f16  = (_Float16*)(ws + 0);               // 17,408,000 B
    float*          oa_f32 = (float*)(ws + 17408000);           // 25,165,824 B
    unsigned short* WtVh   = (unsigned short*)(ws + 42573824);  //    131,072 B
    unsigned short* WtVl   = (unsigned short*)(ws + 42704896);  //    131,072 B
    unsigned short* WtOAh  = (unsigned short*)(ws + 42835968);  //    196,608 B
    unsigned short* WtOAl  = (unsigned short*)(ws + 43032576);  //    196,608 B
    unsigned short* WtOh   = (unsigned short*)(ws + 43229184);  //    131,072 B
    unsigned short* WtOl   = (unsigned short*)(ws + 43360256);  //    131,072 B
    float*          biasOA = (float*)(ws + 43491328);           //      1,536 B

    prep_kernel<<<896, 256, 0, stream>>>(W_v, W_off, W_attn, W_o, b_off, b_attn,
                                         WtVh, WtVl, WtOAh, WtOAl, WtOh, WtOl, biasOA);
    // dual: v = value@W_v + b_v (fp16 head-major)  AND  oa = query@[W_off|W_attn] + bias
    gemm_dual_kernel<<<916, 256, 0, stream>>>(
        value, WtVh, WtVl, b_v, v_f16,
        query, WtOAh, WtOAl, biasOA, oa_f32);
    // fused: softmax + bilinear gather + out-GEMM
    sample_out_kernel<<<NQ / 16, 256, 0, stream>>>(
        v_f16, oa_f32, refp, WtOh, WtOl, b_o, (float*)d_out);
}

// Round 7
// 220.147 us; speedup vs baseline: 1.0951x; 1.0951x over previous
//
#include <hip/hip_runtime.h>

#define NH 8
#define HD 32
#define SUMP 16
#define LQ 4096
#define BS 4
#define LV 8500
#define NQ (BS * LQ)   // 16384
#define MV (BS * LV)   // 34000

typedef float f32x4 __attribute__((ext_vector_type(4)));
typedef _Float16 f16x8 __attribute__((ext_vector_type(8)));

// ---------- prep: weights -> fp16 fragment-linear; bias concat ----------
// frag-linear: unit block (T = n>>4, C = k>>5) of 512 fp16 at offset (T*8+C)*512;
// within: lane16 = (n&15) + 16*((k>>3)&3) at lane16*8, elem = k&7.
__global__ __launch_bounds__(256) void prep_kernel(
    const float* __restrict__ Wv, const float* __restrict__ Woff,
    const float* __restrict__ Wattn, const float* __restrict__ Wo,
    const float* __restrict__ boff, const float* __restrict__ battn,
    _Float16* __restrict__ WtVf, _Float16* __restrict__ WtOAf,
    _Float16* __restrict__ WtOf, float* __restrict__ biasOA)
{
    int g = blockIdx.x * 256 + threadIdx.x;    // 0..229375
    int gl; const _Float16* dummy; _Float16* dst; int which;
    if (g < 65536)       { gl = g;          dst = WtVf;  which = 0; }
    else if (g < 163840) { gl = g - 65536;  dst = WtOAf; which = 1; }
    else                 { gl = g - 163840; dst = WtOf;  which = 2; }
    int e = gl & 7, m16 = (gl >> 3) & 15, q = (gl >> 7) & 3, C = (gl >> 9) & 7, T = gl >> 12;
    int n = T * 16 + m16, k = C * 32 + q * 8 + e;
    float w;
    if (which == 0)      w = Wv[k * 256 + n];
    else if (which == 1) w = (n < 256) ? Woff[k * 256 + n] : Wattn[k * 128 + (n - 256)];
    else                 w = Wo[k * 256 + n];
    dst[gl] = (_Float16)w;
    if (blockIdx.x == 0) biasOA[threadIdx.x] = boff[threadIdx.x];
    if (blockIdx.x == 1 && threadIdx.x < 128) biasOA[256 + threadIdx.x] = battn[threadIdx.x];
}

// ---------- GEMM: LDS-A (XOR swizzle, conflict-free) + frag-linear global B ----------
// Block 128x128, 4 waves 2x2, wave tile 64x64, K=256, BK=32, fp16 MFMA.
template <bool V_MODE>
__device__ __forceinline__ void gemm_body(
    const float* __restrict__ A, const _Float16* __restrict__ Bf,
    const float* __restrict__ bias, void* __restrict__ Cv,
    int M, int mb, int nb, _Float16* As /* 2*4096 fp16 */)
{
    const int t = threadIdx.x;
    const int wave = t >> 6, lane = t & 63;
    const int quad = lane >> 4, l16 = lane & 15;
    const int mbase = mb * 128 + (wave & 1) * 64;
    const int ntile0 = nb * 8 + (wave >> 1) * 4;

    // A staging coords: row = t>>2 (+64), kq = t&3. Swizzled slot (fp16 units):
    const int srow = t >> 2, skq = t & 3;
    int gm0 = mb * 128 + srow;        if (gm0 > M - 1) gm0 = M - 1;
    int gm1 = mb * 128 + srow + 64;   if (gm1 > M - 1) gm1 = M - 1;
    const float* ap0 = A + (size_t)gm0 * 256 + skq * 8;
    const float* ap1 = A + (size_t)gm1 * 256 + skq * 8;
    const int slot0 = (((srow >> 4)) * 64 + skq * 16 + ((srow & 15) ^ skq)) * 8;
    const int slot1 = ((((srow + 64) >> 4)) * 64 + skq * 16 + ((srow & 15) ^ skq)) * 8;

    const _Float16* bp[4];
    #pragma unroll
    for (int ni = 0; ni < 4; ++ni)
        bp[ni] = Bf + (size_t)(ntile0 + ni) * 4096 + lane * 8;

    float a0[8], a1[8];
    f16x8 bcur[4], bnxt[4];
    f32x4 acc[4][4] = {};

    *(float4*)(a0 + 0) = *(const float4*)(ap0 + 0);
    *(float4*)(a0 + 4) = *(const float4*)(ap0 + 4);
    *(float4*)(a1 + 0) = *(const float4*)(ap1 + 0);
    *(float4*)(a1 + 4) = *(const float4*)(ap1 + 4);
    #pragma unroll
    for (int ni = 0; ni < 4; ++ni) bcur[ni] = *(const f16x8*)(bp[ni]);

    #pragma unroll
    for (int k = 0; k < 8; ++k) {
        _Float16* buf = As + (k & 1) * 4096;
        f16x8 c0, c1;
        #pragma unroll
        for (int j = 0; j < 8; ++j) { c0[j] = (_Float16)a0[j]; c1[j] = (_Float16)a1[j]; }
        *(f16x8*)(buf + slot0) = c0;
        *(f16x8*)(buf + slot1) = c1;
        __syncthreads();
        if (k < 7) {
            const int k0 = (k + 1) * 32;
            *(float4*)(a0 + 0) = *(const float4*)(ap0 + k0);
            *(float4*)(a0 + 4) = *(const float4*)(ap0 + k0 + 4);
            *(float4*)(a1 + 0) = *(const float4*)(ap1 + k0);
            *(float4*)(a1 + 4) = *(const float4*)(ap1 + k0 + 4);
            #pragma unroll
            for (int ni = 0; ni < 4; ++ni) bnxt[ni] = *(const f16x8*)(bp[ni] + (k + 1) * 512);
        }
        f16x8 af[4];
        #pragma unroll
        for (int mi = 0; mi < 4; ++mi)
            af[mi] = *(const f16x8*)(buf + (((wave & 1) * 4 + mi) * 64 + quad * 16 + (l16 ^ quad)) * 8);
        #pragma unroll
        for (int mi = 0; mi < 4; ++mi)
            #pragma unroll
            for (int ni = 0; ni < 4; ++ni)
                acc[mi][ni] = __builtin_amdgcn_mfma_f32_16x16x32_f16(af[mi], bcur[ni], acc[mi][ni], 0, 0, 0);
        #pragma unroll
        for (int ni = 0; ni < 4; ++ni) bcur[ni] = bnxt[ni];
    }

    // epilogue: C/D col = l16, row = quad*4+r
    if (V_MODE) {
        #pragma unroll
        for (int mi = 0; mi < 4; ++mi) {
            int mq = mbase + mi * 16 + quad * 4;
            size_t rb[4]; int vld[4];
            #pragma unroll
            for (int r = 0; r < 4; ++r) {
                int m = mq + r;
                vld[r] = (m < M);
                int b = m / LV; int pos = m - b * LV;
                rb[r] = ((size_t)b * NH * LV + pos) * 32;
            }
            #pragma unroll
            for (int ni = 0; ni < 4; ++ni) {
                int n = (ntile0 + ni) * 16 + l16;
                float bv = bias[n];
                int h = n >> 5, d = n & 31;
                size_t ho = (size_t)h * (LV * 32) + d;
                #pragma unroll
                for (int r = 0; r < 4; ++r)
                    if (vld[r]) ((_Float16*)Cv)[rb[r] + ho] = (_Float16)(acc[mi][ni][r] + bv);
            }
        }
    } else {
        #pragma unroll
        for (int ni = 0; ni < 4; ++ni) {
            int n = (ntile0 + ni) * 16 + l16;
            float bv = bias[n];
            #pragma unroll
            for (int mi = 0; mi < 4; ++mi) {
                int mq = mbase + mi * 16 + quad * 4;
                #pragma unroll
                for (int r = 0; r < 4; ++r)
                    ((float*)Cv)[(size_t)(mq + r) * 384 + n] = acc[mi][ni][r] + bv;
            }
        }
    }
}

__global__ __launch_bounds__(256) void gemm_dual_kernel(
    const float* __restrict__ value, const _Float16* __restrict__ WtVf,
    const float* __restrict__ b_v, _Float16* __restrict__ v_f16,
    const float* __restrict__ query, const _Float16* __restrict__ WtOAf,
    const float* __restrict__ biasOA, float* __restrict__ oa)
{
    __shared__ __align__(16) _Float16 As[2 * 4096];
    int bid = blockIdx.x;
    if (bid < 532) {          // V: 266 mb x 2 nb
        gemm_body<true>(value, WtVf, b_v, v_f16, MV, bid % 266, bid / 266, As);
    } else {                  // OA: 128 mb x 3 nb
        int q = bid - 532;
        gemm_body<false>(query, WtOAf, biasOA, oa, NQ, q % 128, q / 128, As);
    }
}

// ---------- fused sampling + output GEMM: 8 queries per block ----------
__global__ __launch_bounds__(256) void sample_out_kernel(
    const _Float16* __restrict__ v,          // [b][h][LV][32] fp16
    const float* __restrict__ oa,            // [NQ][384]: 0..255 offsets, 256..383 logits
    const float* __restrict__ refp,          // [NQ][4]
    const _Float16* __restrict__ WtOf,       // frag-linear
    const float* __restrict__ b_o,
    float* __restrict__ out)                 // [NQ][256] fp32
{
    const int row0 = blockIdx.x * 8;
    const int t = threadIdx.x;
    const int wave = t >> 6, lane = t & 63;
    const int quad = lane >> 4, l16 = lane & 15;

    __shared__ __align__(16) char smem[35072];
    float*  s_lx  = (float*)smem;                     // [8][128]   (union A: 12288)
    float*  s_ly  = (float*)(smem + 4096);
    float*  s_raw = (float*)(smem + 8192);
    int*    s_idx = (int*)smem;                       // [8*8][17]  (union B: 26112)
    int*    s_dxy = (int*)(smem + 4352);
    float4* s_w4  = (float4*)(smem + 8704);
    float*  s_mx  = (float*)(smem + 26112);           // [64]
    float*  s_is  = (float*)(smem + 26368);
    _Float16* s_mid = (_Float16*)(smem + 26624);      // [16][264] fp16 (rows 8..15 garbage)

    // --- P1: locations + raw logits (1024 entries, 4/thread) ---
    #pragma unroll
    for (int it = 0; it < 4; ++it) {
        int i = t + it * 256;
        int q = i >> 7, e = i & 127;          // e = h*16 + p
        int row = row0 + q;
        float4 r4 = *(const float4*)(refp + (size_t)row * 4);
        float2 o2 = *(const float2*)(oa + (size_t)row * 384 + e * 2);
        s_lx[q * 128 + e]  = r4.x + o2.x * 0.125f * r4.z;
        s_ly[q * 128 + e]  = r4.y + o2.y * 0.125f * r4.w;
        s_raw[q * 128 + e] = oa[(size_t)row * 384 + 256 + e];
    }
    __syncthreads();
    // --- P2: softmax stats, one (q,h) per thread ---
    if (t < 64) {
        int q = t >> 3, h = t & 7;
        float mx = -1e30f;
        #pragma unroll
        for (int p = 0; p < SUMP; ++p) mx = fmaxf(mx, s_raw[q * 128 + h * 16 + p]);
        float sm = 0.f;
        #pragma unroll
        for (int p = 0; p < SUMP; ++p) sm += __expf(s_raw[q * 128 + h * 16 + p] - mx);
        s_mx[t] = mx; s_is[t] = 1.f / sm;
    }
    __syncthreads();
    // --- P3: corner weights + offsets to regs, then overlay store ---
    int r_idx[4], r_dxy[4];
    float4 r_w4[4];
    #pragma unroll
    for (int it = 0; it < 4; ++it) {
        int i = t + it * 256;
        int q = i >> 7, e = i & 127, h = e >> 4, p = e & 15, l = p >> 2;
        int Wl = 80 >> l;
        int vst = (l == 0) ? 0 : (l == 1) ? 6400 : (l == 2) ? 8000 : 8400;
        float w = __expf(s_raw[q * 128 + e] - s_mx[q * 8 + h]) * s_is[q * 8 + h];
        float x = s_lx[q * 128 + e] * Wl - 0.5f;
        float y = s_ly[q * 128 + e] * Wl - 0.5f;
        float x0f = floorf(x), y0f = floorf(y);
        float lx = x - x0f, ly = y - y0f;
        int x0 = (int)x0f, y0 = (int)y0f;
        int x1 = x0 + 1, y1 = y0 + 1;
        float mx0 = (x0 >= 0 && x0 < Wl) ? 1.f : 0.f;
        float mx1 = (x1 >= 0 && x1 < Wl) ? 1.f : 0.f;
        float my0 = (y0 >= 0 && y0 < Wl) ? 1.f : 0.f;
        float my1 = (y1 >= 0 && y1 < Wl) ? 1.f : 0.f;
        int cx0 = min(max(x0, 0), Wl - 1), cx1 = min(max(x1, 0), Wl - 1);
        int cy0 = min(max(y0, 0), Wl - 1), cy1 = min(max(y1, 0), Wl - 1);
        r_idx[it] = (vst + cy0 * Wl + cx0) * 64;
        r_dxy[it] = ((cx1 - cx0) * 64) | (((cy1 - cy0) * Wl * 64) << 16);
        float4 w4;
        w4.x = w * (1.f - lx) * (1.f - ly) * mx0 * my0;
        w4.y = w * lx * (1.f - ly) * mx1 * my0;
        w4.z = w * (1.f - lx) * ly * mx0 * my1;
        w4.w = w * lx * ly * mx1 * my1;
        r_w4[it] = w4;
    }
    __syncthreads();   // union-A reads done before overlay write
    #pragma unroll
    for (int it = 0; it < 4; ++it) {
        int i = t + it * 256;
        int q = i >> 7, e = i & 127, h = e >> 4, p = e & 15;
        int s = (q * 8 + h) * 17 + p;
        s_idx[s] = r_idx[it]; s_dxy[s] = r_dxy[it]; s_w4[s] = r_w4[it];
    }
    __syncthreads();
    // --- P4: gather. lane = q2(1b) | h(3b) | dv2(2b); wave covers 2 queries ---
    {
        const int q2 = lane >> 5, hh = (lane >> 2) & 7, dv2 = lane & 3;
        int q = wave * 2 + q2;
        int row = row0 + q;
        int b = row >> 12;                    // LQ = 4096
        const char* vb = (const char*)v + ((size_t)(b * NH + hh) * LV) * 64 + dv2 * 16;
        float acc8[8] = {};
        #pragma unroll
        for (int p = 0; p < 16; ++p) {
            int s = (q * 8 + hh) * 17 + p;
            int base = s_idx[s];
            int dxy = s_dxy[s];
            int dx = dxy & 0xffff, dy = dxy >> 16;
            float4 w4 = s_w4[s];
            f16x8 g00 = *(const f16x8*)(vb + base);
            f16x8 g01 = *(const f16x8*)(vb + base + dx);
            f16x8 g10 = *(const f16x8*)(vb + base + dy);
            f16x8 g11 = *(const f16x8*)(vb + base + dx + dy);
            #pragma unroll
            for (int c = 0; c < 8; ++c)
                acc8[c] += w4.x * (float)g00[c] + w4.y * (float)g01[c]
                         + w4.z * (float)g10[c] + w4.w * (float)g11[c];
        }
        _Float16* mo = s_mid + q * 264 + hh * 32 + dv2 * 8;
        f16x8 m8;
        #pragma unroll
        for (int c = 0; c < 8; ++c) m8[c] = (_Float16)acc8[c];
        *(f16x8*)mo = m8;
    }
    __syncthreads();
    // --- P5: out = mid @ W_o + b_o (A: s_mid fp16; B: frag-linear global) ---
    {
        f32x4 acc[4] = {};
        #pragma unroll
        for (int kc = 0; kc < 8; ++kc) {
            f16x8 af = *(const f16x8*)(s_mid + l16 * 264 + kc * 32 + quad * 8);
            #pragma unroll
            for (int ni = 0; ni < 4; ++ni) {
                f16x8 bf = *(const f16x8*)(WtOf + (size_t)(wave * 4 + ni) * 4096 + kc * 512 + lane * 8);
                acc[ni] = __builtin_amdgcn_mfma_f32_16x16x32_f16(af, bf, acc[ni], 0, 0, 0);
            }
        }
        #pragma unroll
        for (int ni = 0; ni < 4; ++ni) {
            int n = (wave * 4 + ni) * 16 + l16;
            float bv = b_o[n];
            #pragma unroll
            for (int r = 0; r < 4; ++r) {
                int m = quad * 4 + r;
                if (m < 8) out[(size_t)(row0 + m) * 256 + n] = acc[ni][r] + bv;
            }
        }
    }
}

extern "C" void kernel_launch(void* const* d_in, const int* in_sizes, int n_in,
                              void* d_out, int out_size, void* d_ws, size_t ws_size,
                              hipStream_t stream) {
    const float* query  = (const float*)d_in[0];   // [4,4096,256]
    const float* refp   = (const float*)d_in[1];   // [4,4096,1,4]
    const float* value  = (const float*)d_in[2];   // [4,8500,256]
    const float* W_off  = (const float*)d_in[3];   // [256,256]
    const float* b_off  = (const float*)d_in[4];   // [256]
    const float* W_attn = (const float*)d_in[5];   // [256,128]
    const float* b_attn = (const float*)d_in[6];   // [128]
    const float* W_v    = (const float*)d_in[7];   // [256,256]
    const float* b_v    = (const float*)d_in[8];   // [256]
    const float* W_o    = (const float*)d_in[9];   // [256,256]
    const float* b_o    = (const float*)d_in[10];  // [256]

    char* ws = (char*)d_ws;
    _Float16* v_f16  = (_Float16*)(ws + 0);               // 17,408,000 B
    float*    oa_f32 = (float*)(ws + 17408000);           // 25,165,824 B
    _Float16* WtVf   = (_Float16*)(ws + 42573824);        //    131,072 B
    _Float16* WtOAf  = (_Float16*)(ws + 42704896);        //    196,608 B
    _Float16* WtOf   = (_Float16*)(ws + 42901504);        //    131,072 B
    float*    biasOA = (float*)(ws + 43032576);           //      1,536 B

    prep_kernel<<<896, 256, 0, stream>>>(W_v, W_off, W_attn, W_o, b_off, b_attn,
                                         WtVf, WtOAf, WtOf, biasOA);
    gemm_dual_kernel<<<916, 256, 0, stream>>>(
        value, WtVf, b_v, v_f16, query, WtOAf, biasOA, oa_f32);
    sample_out_kernel<<<NQ / 8, 256, 0, stream>>>(
        v_f16, oa_f32, refp, WtOf, b_o, (float*)d_out);
}